// Round 7
// baseline (30.774 us; speedup 1.0000x reference)
//
#include <hip/hip_runtime.h>

// Problem constants (fixed by the reference setup)
#define BB 8
#define LL 4096
#define DD 1024
#define KK 2048

#define RPB 8               // output rows per block
#define NWORDS (LL / 64)    // 64 u64 words per batch bitmap

typedef float f32x4 __attribute__((ext_vector_type(4)));

// Single fused kernel (R4 structure, NT hints removed for A/B).
// Each block:
//  1) rebuilds the batch's 4096-bit boundary bitmap (16 coalesced loads +
//     __ballot per wave -> 64 u64 words in LDS; mask is L2-resident, cheap),
//  2) prefix-scans the 64 popcounts (one wave, shfl scan),
//  3) selects the source row for each of its 8 output rows: k-th set bit if
//     k < num_tokens, else (k-num_tokens)-th clear bit -- exactly the stable
//     compaction order of argsort(i + (~bm)*L)[:K] (unique keys),
//  4) streams 8 rows x 4 KiB with plain float4 copies, and writes its
//     8 next_mask floats.
__global__ void __launch_bounds__(256)
fused_gather_kernel(const f32x4* __restrict__ src,
                    const int* __restrict__ bm,
                    f32x4* __restrict__ dst,
                    float* __restrict__ om) {
    __shared__ unsigned long long words[NWORDS];
    __shared__ int pre[NWORDS];     // popcounts, then inclusive prefix
    __shared__ int srows[RPB];

    const int blk   = blockIdx.x;          // 0 .. 2047
    const int tid   = threadIdx.x;         // 0 .. 255
    const int lane  = tid & 63;
    const int wave  = tid >> 6;            // 0 .. 3
    const int b     = blk >> 8;            // 256 blocks per batch
    const int kbase = (blk & 255) * RPB;   // k offset within batch

    const int* m = bm + (size_t)b * LL;

    // 1) bitmap build: ballot j in wave w covers positions (j*4+w)*64 + lane
#pragma unroll
    for (int j = 0; j < 16; ++j) {
        const unsigned long long w = __ballot(m[j * 256 + tid] != 0);
        if (lane == 0) {
            const int wi = j * 4 + wave;
            words[wi] = w;
            pre[wi]   = __popcll(w);
        }
    }
    __syncthreads();

    // 2) inclusive scan of 64 word-popcounts (wave 0)
    if (wave == 0) {
        int v = pre[lane];
#pragma unroll
        for (int off = 1; off < 64; off <<= 1) {
            const int t = __shfl_up(v, off, 64);
            if (lane >= off) v += t;
        }
        pre[lane] = v;
    }
    __syncthreads();

    const int total = pre[NWORDS - 1];     // num_tokens for batch b

    // 3) per-row source index selection (threads 0..7)
    if (tid < RPB) {
        const int kb = kbase + tid;
        int lo = 0, hi = NWORDS - 1, r;
        unsigned long long x;
        if (kb < total) {
            // smallest word w with pre[w] > kb
            while (lo < hi) { const int mid = (lo + hi) >> 1; if (pre[mid] > kb) hi = mid; else lo = mid + 1; }
            r = kb - ((lo == 0) ? 0 : pre[lo - 1]);
            x = words[lo];
        } else {
            // clear-bit select: zeros_incl[w] = (w+1)*64 - pre[w]
            const int rz = kb - total;
            while (lo < hi) { const int mid = (lo + hi) >> 1; if ((mid + 1) * 64 - pre[mid] > rz) hi = mid; else lo = mid + 1; }
            r = rz - (lo * 64 - ((lo == 0) ? 0 : pre[lo - 1]));
            x = ~words[lo];
        }
        // select r-th (0-based) set bit of x
        int pos = 0;
#pragma unroll
        for (int sh = 32; sh >= 1; sh >>= 1) {
            const int c = __popcll(x & ((1ull << sh) - 1ull));
            if (r >= c) { r -= c; x >>= sh; pos += sh; }
        }
        srows[tid] = lo * 64 + pos;
        om[(size_t)b * KK + kb] = (kb < total) ? 1.0f : 0.0f;
    }
    __syncthreads();

    // 4) stream 8 rows x 4 KiB (coalesced float4, plain cached accesses)
    const size_t srcbase = (size_t)b * LL * (DD / 4);
    const size_t dstbase = ((size_t)b * KK + kbase) * (DD / 4);
    f32x4 v[RPB];
#pragma unroll
    for (int j = 0; j < RPB; ++j)
        v[j] = src[srcbase + (size_t)srows[j] * (DD / 4) + tid];
#pragma unroll
    for (int j = 0; j < RPB; ++j)
        dst[dstbase + (size_t)j * (DD / 4) + tid] = v[j];
}

extern "C" void kernel_launch(void* const* d_in, const int* in_sizes, int n_in,
                              void* d_out, int out_size, void* d_ws, size_t ws_size,
                              hipStream_t stream) {
    const float* hs = (const float*)d_in[0];   // (B, L, D) f32
    const int*   bm = (const int*)d_in[1];     // (B, L) bool -> int32
    // d_in[2] (mask) unused; d_in[3] (next_max_seqlen) fixed at K=2048

    float* out_hs   = (float*)d_out;                        // B*K*D floats
    float* out_mask = (float*)d_out + (size_t)BB * KK * DD; // B*K floats

    fused_gather_kernel<<<(BB * KK) / RPB, 256, 0, stream>>>(
        (const f32x4*)hs, bm, (f32x4*)out_hs, out_mask);
}

// Round 8
// 28.779 us; speedup vs baseline: 1.0693x; 1.0693x over previous
//
#include <hip/hip_runtime.h>

// Problem constants (fixed by the reference setup)
#define BB 8
#define LL 4096
#define DD 1024
#define KK 2048

#define RPB 16              // output rows per block
#define TPB 512             // threads per block (8 waves)
#define NWORDS (LL / 64)    // 64 u64 words per batch bitmap

typedef float f32x4 __attribute__((ext_vector_type(4)));

// Fused kernel, 1024 blocks x 512 threads (4 blocks/CU x 8 waves = 32 waves/CU).
// Identical per-thread copy structure to the best (R4) kernel -- 8 independent
// NT loads then 8 NT stores, threads cooperate across rows (2 rows per step,
// 256 threads each) -- but half the redundant preamble instances.
//  1) bitmap: 8 coalesced dword loads + __ballot -> 64 u64 words in LDS,
//  2) wave 0 prefix-scans the 64 popcounts,
//  3) threads 0-15 binary-search their output row: k-th set bit if
//     k < num_tokens else (k-num_tokens)-th clear bit == stable compaction
//     order of argsort(i + (~bm)*L)[:K] (unique keys),
//  4) copy 16 rows x 4 KiB; next_mask written by threads 0-15.
__global__ void __launch_bounds__(TPB)
fused_gather_kernel(const f32x4* __restrict__ src,
                    const int* __restrict__ bm,
                    f32x4* __restrict__ dst,
                    float* __restrict__ om) {
    __shared__ unsigned long long words[NWORDS];
    __shared__ int pre[NWORDS];     // popcounts, then inclusive prefix
    __shared__ int srows[RPB];

    const int blk   = blockIdx.x;          // 0 .. 1023
    const int tid   = threadIdx.x;         // 0 .. 511
    const int lane  = tid & 63;
    const int wave  = tid >> 6;            // 0 .. 7
    const int b     = blk >> 7;            // 128 blocks per batch
    const int kbase = (blk & 127) * RPB;   // k offset within batch

    const int* m = bm + (size_t)b * LL;

    // 1) bitmap: ballot j in wave w covers positions (j*8+w)*64 + lane
#pragma unroll
    for (int j = 0; j < 8; ++j) {
        const unsigned long long w = __ballot(m[j * TPB + tid] != 0);
        if (lane == 0) {
            const int wi = j * 8 + wave;
            words[wi] = w;
            pre[wi]   = __popcll(w);
        }
    }
    __syncthreads();

    // 2) inclusive scan of 64 word-popcounts (wave 0)
    if (wave == 0) {
        int v = pre[lane];
#pragma unroll
        for (int off = 1; off < 64; off <<= 1) {
            const int t = __shfl_up(v, off, 64);
            if (lane >= off) v += t;
        }
        pre[lane] = v;
    }
    __syncthreads();

    const int total = pre[NWORDS - 1];     // num_tokens for batch b

    // 3) per-row source index selection (threads 0..15)
    if (tid < RPB) {
        const int kb = kbase + tid;
        int lo = 0, hi = NWORDS - 1, r;
        unsigned long long x;
        if (kb < total) {
            // smallest word w with pre[w] > kb
            while (lo < hi) { const int mid = (lo + hi) >> 1; if (pre[mid] > kb) hi = mid; else lo = mid + 1; }
            r = kb - ((lo == 0) ? 0 : pre[lo - 1]);
            x = words[lo];
        } else {
            // clear-bit select: zeros_incl[w] = (w+1)*64 - pre[w]
            const int rz = kb - total;
            while (lo < hi) { const int mid = (lo + hi) >> 1; if ((mid + 1) * 64 - pre[mid] > rz) hi = mid; else lo = mid + 1; }
            r = rz - (lo * 64 - ((lo == 0) ? 0 : pre[lo - 1]));
            x = ~words[lo];
        }
        // select r-th (0-based) set bit of x
        int pos = 0;
#pragma unroll
        for (int sh = 32; sh >= 1; sh >>= 1) {
            const int c = __popcll(x & ((1ull << sh) - 1ull));
            if (r >= c) { r -= c; x >>= sh; pos += sh; }
        }
        srows[tid] = lo * 64 + pos;
        om[(size_t)b * KK + kb] = (kb < total) ? 1.0f : 0.0f;
    }
    __syncthreads();

    // 4) copy: 8 steps x 2 rows (tid>>8 selects row half, tid&255 the column)
    const int half = tid >> 8;             // 0 or 1
    const int col  = tid & 255;
    const size_t srcbase = (size_t)b * LL * (DD / 4);
    f32x4 v[8];
#pragma unroll
    for (int j = 0; j < 8; ++j)
        v[j] = __builtin_nontemporal_load(
            &src[srcbase + (size_t)srows[j * 2 + half] * (DD / 4) + col]);
    f32x4* d = dst + ((size_t)b * KK + kbase + half) * (DD / 4) + col;
#pragma unroll
    for (int j = 0; j < 8; ++j)
        __builtin_nontemporal_store(v[j], &d[(size_t)(j * 2) * (DD / 4)]);
}

extern "C" void kernel_launch(void* const* d_in, const int* in_sizes, int n_in,
                              void* d_out, int out_size, void* d_ws, size_t ws_size,
                              hipStream_t stream) {
    const float* hs = (const float*)d_in[0];   // (B, L, D) f32
    const int*   bm = (const int*)d_in[1];     // (B, L) bool -> int32
    // d_in[2] (mask) unused; d_in[3] (next_max_seqlen) fixed at K=2048

    float* out_hs   = (float*)d_out;                        // B*K*D floats
    float* out_mask = (float*)d_out + (size_t)BB * KK * DD; // B*K floats

    fused_gather_kernel<<<(BB * KK) / RPB, TPB, 0, stream>>>(
        (const f32x4*)hs, bm, (f32x4*)out_hs, out_mask);
}

// Round 9
// 28.410 us; speedup vs baseline: 1.0832x; 1.0130x over previous
//
#include <hip/hip_runtime.h>

// Problem constants (fixed by the reference setup)
#define BB 8
#define LL 4096
#define DD 1024
#define KK 2048

#define RPB 16              // output rows per block
#define TPB 512             // threads per block (8 waves)
#define NWORDS (LL / 64)    // 64 u64 words per batch bitmap

typedef float f32x4 __attribute__((ext_vector_type(4)));

// Fused kernel, 1024 blocks x 512 threads (4 blocks/CU x 8 waves = 32 waves/CU).
// R8 structure; A/B: loads plain cached (was NT), stores stay NT.
//  1) bitmap: 8 coalesced dword loads + __ballot -> 64 u64 words in LDS,
//  2) wave 0 prefix-scans the 64 popcounts,
//  3) threads 0-15 binary-search their output row: k-th set bit if
//     k < num_tokens else (k-num_tokens)-th clear bit == stable compaction
//     order of argsort(i + (~bm)*L)[:K] (unique keys),
//  4) copy 16 rows x 4 KiB; next_mask written by threads 0-15.
__global__ void __launch_bounds__(TPB)
fused_gather_kernel(const f32x4* __restrict__ src,
                    const int* __restrict__ bm,
                    f32x4* __restrict__ dst,
                    float* __restrict__ om) {
    __shared__ unsigned long long words[NWORDS];
    __shared__ int pre[NWORDS];     // popcounts, then inclusive prefix
    __shared__ int srows[RPB];

    const int blk   = blockIdx.x;          // 0 .. 1023
    const int tid   = threadIdx.x;         // 0 .. 511
    const int lane  = tid & 63;
    const int wave  = tid >> 6;            // 0 .. 7
    const int b     = blk >> 7;            // 128 blocks per batch
    const int kbase = (blk & 127) * RPB;   // k offset within batch

    const int* m = bm + (size_t)b * LL;

    // 1) bitmap: ballot j in wave w covers positions (j*8+w)*64 + lane
#pragma unroll
    for (int j = 0; j < 8; ++j) {
        const unsigned long long w = __ballot(m[j * TPB + tid] != 0);
        if (lane == 0) {
            const int wi = j * 8 + wave;
            words[wi] = w;
            pre[wi]   = __popcll(w);
        }
    }
    __syncthreads();

    // 2) inclusive scan of 64 word-popcounts (wave 0)
    if (wave == 0) {
        int v = pre[lane];
#pragma unroll
        for (int off = 1; off < 64; off <<= 1) {
            const int t = __shfl_up(v, off, 64);
            if (lane >= off) v += t;
        }
        pre[lane] = v;
    }
    __syncthreads();

    const int total = pre[NWORDS - 1];     // num_tokens for batch b

    // 3) per-row source index selection (threads 0..15)
    if (tid < RPB) {
        const int kb = kbase + tid;
        int lo = 0, hi = NWORDS - 1, r;
        unsigned long long x;
        if (kb < total) {
            // smallest word w with pre[w] > kb
            while (lo < hi) { const int mid = (lo + hi) >> 1; if (pre[mid] > kb) hi = mid; else lo = mid + 1; }
            r = kb - ((lo == 0) ? 0 : pre[lo - 1]);
            x = words[lo];
        } else {
            // clear-bit select: zeros_incl[w] = (w+1)*64 - pre[w]
            const int rz = kb - total;
            while (lo < hi) { const int mid = (lo + hi) >> 1; if ((mid + 1) * 64 - pre[mid] > rz) hi = mid; else lo = mid + 1; }
            r = rz - (lo * 64 - ((lo == 0) ? 0 : pre[lo - 1]));
            x = ~words[lo];
        }
        // select r-th (0-based) set bit of x
        int pos = 0;
#pragma unroll
        for (int sh = 32; sh >= 1; sh >>= 1) {
            const int c = __popcll(x & ((1ull << sh) - 1ull));
            if (r >= c) { r -= c; x >>= sh; pos += sh; }
        }
        srows[tid] = lo * 64 + pos;
        om[(size_t)b * KK + kb] = (kb < total) ? 1.0f : 0.0f;
    }
    __syncthreads();

    // 4) copy: 8 steps x 2 rows (tid>>8 selects row half, tid&255 the column)
    const int half = tid >> 8;             // 0 or 1
    const int col  = tid & 255;
    const size_t srcbase = (size_t)b * LL * (DD / 4);
    f32x4 v[8];
#pragma unroll
    for (int j = 0; j < 8; ++j)
        v[j] = src[srcbase + (size_t)srows[j * 2 + half] * (DD / 4) + col];
    f32x4* d = dst + ((size_t)b * KK + kbase + half) * (DD / 4) + col;
#pragma unroll
    for (int j = 0; j < 8; ++j)
        __builtin_nontemporal_store(v[j], &d[(size_t)(j * 2) * (DD / 4)]);
}

extern "C" void kernel_launch(void* const* d_in, const int* in_sizes, int n_in,
                              void* d_out, int out_size, void* d_ws, size_t ws_size,
                              hipStream_t stream) {
    const float* hs = (const float*)d_in[0];   // (B, L, D) f32
    const int*   bm = (const int*)d_in[1];     // (B, L) bool -> int32
    // d_in[2] (mask) unused; d_in[3] (next_max_seqlen) fixed at K=2048

    float* out_hs   = (float*)d_out;                        // B*K*D floats
    float* out_mask = (float*)d_out + (size_t)BB * KK * DD; // B*K floats

    fused_gather_kernel<<<(BB * KK) / RPB, TPB, 0, stream>>>(
        (const f32x4*)hs, bm, (f32x4*)out_hs, out_mask);
}

// Round 10
// 27.304 us; speedup vs baseline: 1.1271x; 1.0405x over previous
//
#include <hip/hip_runtime.h>

// Problem constants (fixed by the reference setup)
#define BB 8
#define LL 4096
#define DD 1024
#define KK 2048

#define RPB 32              // output rows per block
#define TPB 1024            // threads per block (16 waves)
#define NWORDS (LL / 64)    // 64 u64 words per batch bitmap

typedef float f32x4 __attribute__((ext_vector_type(4)));

// Fused kernel, 512 blocks x 1024 threads (2 blocks/CU x 16 waves = 32 waves/CU).
// R9 structure (cached loads, NT stores); preamble instances halved again.
//  1) bitmap: 4 coalesced dword loads + __ballot -> 64 u64 words in LDS,
//  2) wave 0 prefix-scans the 64 popcounts,
//  3) threads 0-31 binary-search their output row: k-th set bit if
//     k < num_tokens else (k-num_tokens)-th clear bit == stable compaction
//     order of argsort(i + (~bm)*L)[:K] (unique keys),
//  4) copy 32 rows x 4 KiB; next_mask written by threads 0-31.
__global__ void __launch_bounds__(TPB)
fused_gather_kernel(const f32x4* __restrict__ src,
                    const int* __restrict__ bm,
                    f32x4* __restrict__ dst,
                    float* __restrict__ om) {
    __shared__ unsigned long long words[NWORDS];
    __shared__ int pre[NWORDS];     // popcounts, then inclusive prefix
    __shared__ int srows[RPB];

    const int blk   = blockIdx.x;          // 0 .. 511
    const int tid   = threadIdx.x;         // 0 .. 1023
    const int lane  = tid & 63;
    const int wave  = tid >> 6;            // 0 .. 15
    const int b     = blk >> 6;            // 64 blocks per batch
    const int kbase = (blk & 63) * RPB;    // k offset within batch

    const int* m = bm + (size_t)b * LL;

    // 1) bitmap: ballot j in wave w covers positions (j*16+w)*64 + lane
#pragma unroll
    for (int j = 0; j < 4; ++j) {
        const unsigned long long w = __ballot(m[j * TPB + tid] != 0);
        if (lane == 0) {
            const int wi = j * 16 + wave;
            words[wi] = w;
            pre[wi]   = __popcll(w);
        }
    }
    __syncthreads();

    // 2) inclusive scan of 64 word-popcounts (wave 0)
    if (wave == 0) {
        int v = pre[lane];
#pragma unroll
        for (int off = 1; off < 64; off <<= 1) {
            const int t = __shfl_up(v, off, 64);
            if (lane >= off) v += t;
        }
        pre[lane] = v;
    }
    __syncthreads();

    const int total = pre[NWORDS - 1];     // num_tokens for batch b

    // 3) per-row source index selection (threads 0..31)
    if (tid < RPB) {
        const int kb = kbase + tid;
        int lo = 0, hi = NWORDS - 1, r;
        unsigned long long x;
        if (kb < total) {
            // smallest word w with pre[w] > kb
            while (lo < hi) { const int mid = (lo + hi) >> 1; if (pre[mid] > kb) hi = mid; else lo = mid + 1; }
            r = kb - ((lo == 0) ? 0 : pre[lo - 1]);
            x = words[lo];
        } else {
            // clear-bit select: zeros_incl[w] = (w+1)*64 - pre[w]
            const int rz = kb - total;
            while (lo < hi) { const int mid = (lo + hi) >> 1; if ((mid + 1) * 64 - pre[mid] > rz) hi = mid; else lo = mid + 1; }
            r = rz - (lo * 64 - ((lo == 0) ? 0 : pre[lo - 1]));
            x = ~words[lo];
        }
        // select r-th (0-based) set bit of x
        int pos = 0;
#pragma unroll
        for (int sh = 32; sh >= 1; sh >>= 1) {
            const int c = __popcll(x & ((1ull << sh) - 1ull));
            if (r >= c) { r -= c; x >>= sh; pos += sh; }
        }
        srows[tid] = lo * 64 + pos;
        om[(size_t)b * KK + kb] = (kb < total) ? 1.0f : 0.0f;
    }
    __syncthreads();

    // 4) copy: 8 steps x 4 rows (tid>>8 selects row quarter, tid&255 column)
    const int quarter = tid >> 8;          // 0 .. 3
    const int col     = tid & 255;
    const size_t srcbase = (size_t)b * LL * (DD / 4);
    f32x4 v[8];
#pragma unroll
    for (int j = 0; j < 8; ++j)
        v[j] = src[srcbase + (size_t)srows[j * 4 + quarter] * (DD / 4) + col];
    f32x4* d = dst + ((size_t)b * KK + kbase + quarter) * (DD / 4) + col;
#pragma unroll
    for (int j = 0; j < 8; ++j)
        __builtin_nontemporal_store(v[j], &d[(size_t)(j * 4) * (DD / 4)]);
}

extern "C" void kernel_launch(void* const* d_in, const int* in_sizes, int n_in,
                              void* d_out, int out_size, void* d_ws, size_t ws_size,
                              hipStream_t stream) {
    const float* hs = (const float*)d_in[0];   // (B, L, D) f32
    const int*   bm = (const int*)d_in[1];     // (B, L) bool -> int32
    // d_in[2] (mask) unused; d_in[3] (next_max_seqlen) fixed at K=2048

    float* out_hs   = (float*)d_out;                        // B*K*D floats
    float* out_mask = (float*)d_out + (size_t)BB * KK * DD; // B*K floats

    fused_gather_kernel<<<(BB * KK) / RPB, TPB, 0, stream>>>(
        (const f32x4*)hs, bm, (f32x4*)out_hs, out_mask);
}